// Round 1
// baseline (637.766 us; speedup 1.0000x reference)
//
#include <hip/hip_runtime.h>
#include <hip/hip_bf16.h>
#include <math.h>

#define B 4
#define N 2048
#define FIN 256
#define H 4
#define FO 64
#define M (B*N)        // 8192 rows
#define HF (H*FO)      // 256 cols

// ---------------- Kernel 1: Hout = X @ W  (M x FIN)(FIN x HF) fp32 tiled ----
__global__ __launch_bounds__(256) void gemm_xw(const float* __restrict__ X,
                                               const float* __restrict__ W,
                                               float* __restrict__ Hout) {
  __shared__ float As[16][64];   // [k][m]
  __shared__ float Bs[16][64];   // [k][n]
  const int tid = threadIdx.x;
  const int m0 = (blockIdx.x >> 2) * 64;   // grid.x = (M/64)*(HF/64) = 128*4 = 512
  const int n0 = (blockIdx.x & 3) * 64;
  const int tm = tid >> 4;    // 0..15
  const int tn = tid & 15;    // 0..15
  float acc[4][4] = {};
  for (int k0 = 0; k0 < FIN; k0 += 16) {
    {
      const int r  = tid >> 2;         // 0..63 (m)
      const int c4 = (tid & 3) * 4;    // 0,4,8,12 (k)
      const float4 va = *(const float4*)(X + (size_t)(m0 + r) * FIN + k0 + c4);
      As[c4 + 0][r] = va.x; As[c4 + 1][r] = va.y;
      As[c4 + 2][r] = va.z; As[c4 + 3][r] = va.w;
    }
    {
      const int r  = tid >> 4;         // 0..15 (k)
      const int c4 = (tid & 15) * 4;   // 0..60 (n)
      *(float4*)&Bs[r][c4] = *(const float4*)(W + (size_t)(k0 + r) * HF + n0 + c4);
    }
    __syncthreads();
    #pragma unroll
    for (int k = 0; k < 16; ++k) {
      float a[4], b[4];
      #pragma unroll
      for (int x = 0; x < 4; ++x) a[x] = As[k][tm * 4 + x];
      #pragma unroll
      for (int x = 0; x < 4; ++x) b[x] = Bs[k][tn * 4 + x];
      #pragma unroll
      for (int x = 0; x < 4; ++x)
        #pragma unroll
        for (int y = 0; y < 4; ++y)
          acc[x][y] = fmaf(a[x], b[y], acc[x][y]);
    }
    __syncthreads();
  }
  #pragma unroll
  for (int x = 0; x < 4; ++x) {
    float4 v = make_float4(acc[x][0], acc[x][1], acc[x][2], acc[x][3]);
    *(float4*)(Hout + (size_t)(m0 + tm * 4 + x) * HF + n0 + tn * 4) = v;
  }
}

// ------------- Kernel 2: per-(b,n,h) dots with a_src/a_dst -----------------
// Src/Dst stored as (B,H,N) for coalesced j-scans in the attention kernel.
__global__ __launch_bounds__(256) void attn_sd(const float* __restrict__ Hout,
                                               const float* __restrict__ a_src,
                                               const float* __restrict__ a_dst,
                                               float* __restrict__ Src,
                                               float* __restrict__ Dst) {
  const int m = blockIdx.x;          // b*N+n
  const int t = threadIdx.x;
  const int h = t >> 6, f = t & 63;
  const float v = Hout[(size_t)m * HF + t];
  float s = v * a_src[h * FO + f];
  float d = v * a_dst[h * FO + f];
  #pragma unroll
  for (int off = 32; off > 0; off >>= 1) {
    s += __shfl_down(s, off, 64);
    d += __shfl_down(d, off, 64);
  }
  if (f == 0) {
    const int b = m >> 11, n = m & (N - 1);
    Src[((b * H + h) << 11) + n] = s;
    Dst[((b * H + h) << 11) + n] = d;
  }
}

// ------------- Kernel 3: flash-style masked softmax + aggregation ----------
// One block per (b,i); wave w = head h. Lane layout inside a wave:
//   jg = lane>>4 (j subgroup 0..3), fbase = (lane&15)*4 (f quad)
__global__ __launch_bounds__(256) void gat_attn(const float* __restrict__ Hout,
                                                const float* __restrict__ adj,
                                                const float* __restrict__ Src,
                                                const float* __restrict__ Dst,
                                                float* __restrict__ out) {
  const int blk  = blockIdx.x;       // 0..8191
  const int b    = blk >> 11;
  const int i    = blk & (N - 1);
  const int h    = threadIdx.x >> 6;
  const int lane = threadIdx.x & 63;

  const float  s_i    = Src[((b * H + h) << 11) + i];
  const float* dstp   = Dst + ((b * H + h) << 11);
  const float* adjrow = adj + (size_t)i * N;
  const float* hbase  = Hout + (size_t)(b * N) * HF + h * FO;

  const int jg    = lane >> 4;
  const int fbase = (lane & 15) * 4;

  float m = -INFINITY, l = 0.f;
  float4 acc = make_float4(0.f, 0.f, 0.f, 0.f);

  for (int j0 = 0; j0 < N; j0 += 64) {
    const float a = adjrow[j0 + lane];
    const float d = dstp[j0 + lane];
    float sc = s_i + d;
    sc = fmaxf(sc, 0.2f * sc);                 // leaky_relu slope 0.2
    sc = (a != 0.f) ? sc : -INFINITY;          // mask

    float cm = sc;
    #pragma unroll
    for (int off = 32; off > 0; off >>= 1) cm = fmaxf(cm, __shfl_xor(cm, off, 64));
    const float mnew = fmaxf(m, cm);

    float alpha = 1.f;
    if (mnew != -INFINITY) alpha = __expf(m - mnew);     // m=-inf -> 0, ok
    const float p = (sc == -INFINITY) ? 0.f : __expf(sc - mnew);

    float ps = p;
    #pragma unroll
    for (int off = 32; off > 0; off >>= 1) ps += __shfl_xor(ps, off, 64);
    l = l * alpha + ps;

    acc.x *= alpha; acc.y *= alpha; acc.z *= alpha; acc.w *= alpha;

    #pragma unroll
    for (int g = 0; g < 16; ++g) {
      const int j = 4 * g + jg;                          // j within chunk
      const float pj = __shfl(p, j, 64);                 // broadcast p_j
      const float4 hv = *(const float4*)(hbase + (size_t)(j0 + j) * HF + fbase);
      acc.x = fmaf(pj, hv.x, acc.x);
      acc.y = fmaf(pj, hv.y, acc.y);
      acc.z = fmaf(pj, hv.z, acc.z);
      acc.w = fmaf(pj, hv.w, acc.w);
    }
    m = mnew;
  }

  // combine the 4 j-subgroups: lanes l, l^16, l^32, l^48 hold the same f quad
  #pragma unroll
  for (int off = 16; off <= 32; off <<= 1) {
    acc.x += __shfl_xor(acc.x, off, 64);
    acc.y += __shfl_xor(acc.y, off, 64);
    acc.z += __shfl_xor(acc.z, off, 64);
    acc.w += __shfl_xor(acc.w, off, 64);
  }

  if (jg == 0) {
    const float invl = 1.f / l;
    float4 o = make_float4(acc.x * invl, acc.y * invl, acc.z * invl, acc.w * invl);
    *(float4*)(out + (size_t)(b * N + i) * HF + h * FO + fbase) = o;
  }
}

extern "C" void kernel_launch(void* const* d_in, const int* in_sizes, int n_in,
                              void* d_out, int out_size, void* d_ws, size_t ws_size,
                              hipStream_t stream) {
  const float* x     = (const float*)d_in[0];
  const float* adj   = (const float*)d_in[1];
  const float* W     = (const float*)d_in[2];
  const float* a_src = (const float*)d_in[3];
  const float* a_dst = (const float*)d_in[4];
  float* out = (float*)d_out;

  float* Hout = (float*)d_ws;                       // M*HF floats = 8.4 MB
  float* Src  = Hout + (size_t)M * HF;              // B*H*N floats
  float* Dst  = Src + (size_t)B * H * N;

  gemm_xw<<<dim3((M / 64) * (HF / 64)), dim3(256), 0, stream>>>(x, W, Hout);
  attn_sd<<<dim3(M), dim3(256), 0, stream>>>(Hout, a_src, a_dst, Src, Dst);
  gat_attn<<<dim3(M), dim3(256), 0, stream>>>(Hout, adj, Src, Dst, out);
}

// Round 2
// 211.605 us; speedup vs baseline: 3.0139x; 3.0139x over previous
//
#include <hip/hip_runtime.h>
#include <hip/hip_bf16.h>
#include <math.h>

#define B 4
#define N 2048
#define FIN 256
#define H 4
#define FO 64
#define M (B*N)        // 8192 rows
#define HF (H*FO)      // 256 cols

typedef __attribute__((ext_vector_type(8))) short short8;   // 8 bf16 (4 VGPRs)
typedef __attribute__((ext_vector_type(4))) float float4v;  // MFMA C/D

static __device__ __forceinline__ short f2bf(float f) {
  __hip_bfloat16 h = __float2bfloat16(f);   // RNE
  return __builtin_bit_cast(short, h);
}

// ---------------- Kernel 1: Hout = X @ W  (M x FIN)(FIN x HF) fp32 tiled ----
__global__ __launch_bounds__(256) void gemm_xw(const float* __restrict__ X,
                                               const float* __restrict__ W,
                                               float* __restrict__ Hout) {
  __shared__ float As[16][64];   // [k][m]
  __shared__ float Bs[16][64];   // [k][n]
  const int tid = threadIdx.x;
  const int m0 = (blockIdx.x >> 2) * 64;
  const int n0 = (blockIdx.x & 3) * 64;
  const int tm = tid >> 4;
  const int tn = tid & 15;
  float acc[4][4] = {};
  for (int k0 = 0; k0 < FIN; k0 += 16) {
    {
      const int r  = tid >> 2;
      const int c4 = (tid & 3) * 4;
      const float4 va = *(const float4*)(X + (size_t)(m0 + r) * FIN + k0 + c4);
      As[c4 + 0][r] = va.x; As[c4 + 1][r] = va.y;
      As[c4 + 2][r] = va.z; As[c4 + 3][r] = va.w;
    }
    {
      const int r  = tid >> 4;
      const int c4 = (tid & 15) * 4;
      *(float4*)&Bs[r][c4] = *(const float4*)(W + (size_t)(k0 + r) * HF + n0 + c4);
    }
    __syncthreads();
    #pragma unroll
    for (int k = 0; k < 16; ++k) {
      float a[4], b[4];
      #pragma unroll
      for (int x = 0; x < 4; ++x) a[x] = As[k][tm * 4 + x];
      #pragma unroll
      for (int x = 0; x < 4; ++x) b[x] = Bs[k][tn * 4 + x];
      #pragma unroll
      for (int x = 0; x < 4; ++x)
        #pragma unroll
        for (int y = 0; y < 4; ++y)
          acc[x][y] = fmaf(a[x], b[y], acc[x][y]);
    }
    __syncthreads();
  }
  #pragma unroll
  for (int x = 0; x < 4; ++x) {
    float4 v = make_float4(acc[x][0], acc[x][1], acc[x][2], acc[x][3]);
    *(float4*)(Hout + (size_t)(m0 + tm * 4 + x) * HF + n0 + tn * 4) = v;
  }
}

// ------------- Kernel 2: per-(b,n,h) dots with a_src/a_dst -----------------
// Src/Dst stored (B,H,N) for coalesced j-scans.
__global__ __launch_bounds__(256) void attn_sd(const float* __restrict__ Hout,
                                               const float* __restrict__ a_src,
                                               const float* __restrict__ a_dst,
                                               float* __restrict__ Src,
                                               float* __restrict__ Dst) {
  const int m = blockIdx.x;          // b*N+n
  const int t = threadIdx.x;
  const int h = t >> 6, f = t & 63;
  const float v = Hout[(size_t)m * HF + t];
  float s = v * a_src[h * FO + f];
  float d = v * a_dst[h * FO + f];
  #pragma unroll
  for (int off = 32; off > 0; off >>= 1) {
    s += __shfl_down(s, off, 64);
    d += __shfl_down(d, off, 64);
  }
  if (f == 0) {
    const int b = m >> 11, n = m & (N - 1);
    Src[((b * H + h) << 11) + n] = s;
    Dst[((b * H + h) << 11) + n] = d;
  }
}

// ------------- Kernel 3: transpose Hout -> Ht bf16 [b][h][f][j] ------------
__global__ __launch_bounds__(256) void h2t(const float* __restrict__ Hout,
                                           unsigned short* __restrict__ Ht) {
  __shared__ float lds[64][65];
  const int bh = blockIdx.x >> 5;          // b*H + h
  const int j0 = (blockIdx.x & 31) * 64;
  const int b  = bh >> 2, h = bh & 3;
  const int t  = threadIdx.x;
  // read: rows j (coalesced in f)
  const int c4 = (t & 15) * 4;
  #pragma unroll
  for (int k = 0; k < 4; ++k) {
    const int jj = (t >> 4) + 16 * k;
    const float4 v = *(const float4*)(Hout + (size_t)(b * N + j0 + jj) * HF + h * FO + c4);
    lds[jj][c4 + 0] = v.x; lds[jj][c4 + 1] = v.y;
    lds[jj][c4 + 2] = v.z; lds[jj][c4 + 3] = v.w;
  }
  __syncthreads();
  // write: rows f (coalesced in j), bf16
  const int j = t & 63;
  #pragma unroll
  for (int k = 0; k < 16; ++k) {
    const int f = (t >> 6) + 4 * k;
    Ht[((size_t)bh * FO + f) * N + j0 + j] = (unsigned short)f2bf(lds[j][f]);
  }
}

// ------------- Kernel 4: exact per-row max of masked leaky scores ----------
__global__ __launch_bounds__(256) void row_max(const float* __restrict__ adj,
                                               const float* __restrict__ Src,
                                               const float* __restrict__ Dst,
                                               float* __restrict__ Mrow) {
  const int idx  = blockIdx.x * 4 + (threadIdx.x >> 6);  // (b*H+h)*N + i
  const int lane = threadIdx.x & 63;
  const int bh = idx >> 11, i = idx & (N - 1);
  const float s_i = Src[idx];
  const float* dz = Dst + (bh << 11);
  const float* ar = adj + (size_t)i * N;
  float m = -INFINITY;
  for (int j0 = 0; j0 < N; j0 += 64) {
    const float a = ar[j0 + lane];
    const float d = dz[j0 + lane];
    float sc = s_i + d;
    sc = fmaxf(sc, 0.2f * sc);
    sc = (a != 0.f) ? sc : -INFINITY;
    m = fmaxf(m, sc);
  }
  #pragma unroll
  for (int off = 32; off > 0; off >>= 1) m = fmaxf(m, __shfl_xor(m, off, 64));
  if (lane == 0) Mrow[idx] = m;
}

// ------------- Kernel 5: MFMA flash aggregation ----------------------------
// Block = (b, 16-row i-tile); wave = head h. j streams in chunks of 32 (K dim).
// A-frag (P): lane holds row i0+(lane&15), k = (lane>>4)*8 + jj.
// B-frag (Ht): lane holds col f = 16t+(lane&15), k contiguous.
// 5th accumulator with B=ones gives l_i (row sums of P).
__global__ __launch_bounds__(256) void gat_mfma(const float* __restrict__ adj,
                                                const float* __restrict__ Src,
                                                const float* __restrict__ Dst,
                                                const float* __restrict__ Mrow,
                                                const unsigned short* __restrict__ Ht,
                                                float* __restrict__ out) {
  const int b    = blockIdx.x >> 7;
  const int i0   = (blockIdx.x & 127) * 16;
  const int h    = threadIdx.x >> 6;
  const int lane = threadIdx.x & 63;
  const int bh   = b * H + h;
  const int fl   = lane & 15;        // A-row / B-col within tile
  const int kk   = (lane >> 4) * 8;  // k offset within chunk

  const int   row = i0 + fl;
  const float s_i = Src[(bh << 11) + row];
  const float m_i = Mrow[(bh << 11) + row];
  const float* dz   = Dst + (bh << 11);
  const float* adjr = adj + (size_t)row * N;
  const unsigned short* ht0 = Ht + ((size_t)bh * FO + fl) * N;

  const short onebf = 0x3F80;  // bf16(1.0)
  short8 ones;
  #pragma unroll
  for (int jj = 0; jj < 8; ++jj) ones[jj] = onebf;

  float4v acc0 = {0,0,0,0}, acc1 = {0,0,0,0}, acc2 = {0,0,0,0}, acc3 = {0,0,0,0};
  float4v accL = {0,0,0,0};

  for (int j0 = 0; j0 < N; j0 += 32) {
    const float4 d0 = *(const float4*)(dz + j0 + kk);
    const float4 d1 = *(const float4*)(dz + j0 + kk + 4);
    const float4 a0 = *(const float4*)(adjr + j0 + kk);
    const float4 a1 = *(const float4*)(adjr + j0 + kk + 4);
    const float dv[8] = {d0.x, d0.y, d0.z, d0.w, d1.x, d1.y, d1.z, d1.w};
    const float av[8] = {a0.x, a0.y, a0.z, a0.w, a1.x, a1.y, a1.z, a1.w};
    short8 pf;
    #pragma unroll
    for (int jj = 0; jj < 8; ++jj) {
      float sc = s_i + dv[jj];
      sc = fmaxf(sc, 0.2f * sc);                 // leaky_relu 0.2
      sc = (av[jj] != 0.f) ? sc : -INFINITY;     // mask -> exp gives 0
      pf[jj] = f2bf(__expf(sc - m_i));
    }
    const short8 b0 = *(const short8*)(ht0 + 0 * 16 * N + j0 + kk);
    const short8 b1 = *(const short8*)(ht0 + 1 * 16 * N + j0 + kk);
    const short8 b2 = *(const short8*)(ht0 + 2 * 16 * N + j0 + kk);
    const short8 b3 = *(const short8*)(ht0 + 3 * 16 * N + j0 + kk);
    acc0 = __builtin_amdgcn_mfma_f32_16x16x32_bf16(pf, b0, acc0, 0, 0, 0);
    acc1 = __builtin_amdgcn_mfma_f32_16x16x32_bf16(pf, b1, acc1, 0, 0, 0);
    acc2 = __builtin_amdgcn_mfma_f32_16x16x32_bf16(pf, b2, acc2, 0, 0, 0);
    acc3 = __builtin_amdgcn_mfma_f32_16x16x32_bf16(pf, b3, acc3, 0, 0, 0);
    accL = __builtin_amdgcn_mfma_f32_16x16x32_bf16(pf, ones, accL, 0, 0, 0);
  }

  // C/D layout: col = lane&15, row = (lane>>4)*4 + reg
  const int quad = lane >> 4;
  float4v accs[4] = {acc0, acc1, acc2, acc3};
  #pragma unroll
  for (int reg = 0; reg < 4; ++reg) {
    const int r = quad * 4 + reg;
    const float invl = 1.f / accL[reg];
    float* op = out + ((size_t)(b * N) + i0 + r) * HF + h * FO + fl;
    #pragma unroll
    for (int t = 0; t < 4; ++t) op[t * 16] = accs[t][reg] * invl;
  }
}

extern "C" void kernel_launch(void* const* d_in, const int* in_sizes, int n_in,
                              void* d_out, int out_size, void* d_ws, size_t ws_size,
                              hipStream_t stream) {
  const float* x     = (const float*)d_in[0];
  const float* adj   = (const float*)d_in[1];
  const float* W     = (const float*)d_in[2];
  const float* a_src = (const float*)d_in[3];
  const float* a_dst = (const float*)d_in[4];
  float* out = (float*)d_out;

  float* Hout = (float*)d_ws;                        // 8192*256 f32 = 8 MiB
  float* Src  = Hout + (size_t)M * HF;               // 32768 f32
  float* Dst  = Src + (size_t)B * H * N;             // 32768 f32
  float* Mrow = Dst + (size_t)B * H * N;             // 32768 f32
  unsigned short* Ht = (unsigned short*)(Mrow + (size_t)B * H * N);  // 4 MiB bf16

  gemm_xw<<<dim3((M / 64) * (HF / 64)), dim3(256), 0, stream>>>(x, W, Hout);
  attn_sd<<<dim3(M), dim3(256), 0, stream>>>(Hout, a_src, a_dst, Src, Dst);
  h2t<<<dim3(B * H * (N / 64)), dim3(256), 0, stream>>>(Hout, Ht);
  row_max<<<dim3(B * H * N / 4), dim3(256), 0, stream>>>(adj, Src, Dst, Mrow);
  gat_mfma<<<dim3(B * (N / 16)), dim3(256), 0, stream>>>(adj, Src, Dst, Mrow, Ht, out);
}

// Round 3
// 162.484 us; speedup vs baseline: 3.9251x; 1.3023x over previous
//
#include <hip/hip_runtime.h>
#include <hip/hip_bf16.h>
#include <math.h>

#define B 4
#define N 2048
#define FIN 256
#define H 4
#define FO 64
#define M (B*N)        // 8192 rows
#define HF (H*FO)      // 256 cols

typedef __attribute__((ext_vector_type(8))) short short8;   // 8 bf16 (4 VGPRs)
typedef __attribute__((ext_vector_type(4))) float float4v;  // MFMA C/D

static __device__ __forceinline__ short f2bf(float f) {
  __hip_bfloat16 h = __float2bfloat16(f);   // RNE
  return __builtin_bit_cast(short, h);
}

// ---------------- Kernel 1: Hout = X @ W  (M x FIN)(FIN x HF) fp32 tiled ----
__global__ __launch_bounds__(256) void gemm_xw(const float* __restrict__ X,
                                               const float* __restrict__ W,
                                               float* __restrict__ Hout) {
  __shared__ float As[16][64];   // [k][m]
  __shared__ float Bs[16][64];   // [k][n]
  const int tid = threadIdx.x;
  const int m0 = (blockIdx.x >> 2) * 64;
  const int n0 = (blockIdx.x & 3) * 64;
  const int tm = tid >> 4;
  const int tn = tid & 15;
  float acc[4][4] = {};
  for (int k0 = 0; k0 < FIN; k0 += 16) {
    {
      const int r  = tid >> 2;
      const int c4 = (tid & 3) * 4;
      const float4 va = *(const float4*)(X + (size_t)(m0 + r) * FIN + k0 + c4);
      As[c4 + 0][r] = va.x; As[c4 + 1][r] = va.y;
      As[c4 + 2][r] = va.z; As[c4 + 3][r] = va.w;
    }
    {
      const int r  = tid >> 4;
      const int c4 = (tid & 15) * 4;
      *(float4*)&Bs[r][c4] = *(const float4*)(W + (size_t)(k0 + r) * HF + n0 + c4);
    }
    __syncthreads();
    #pragma unroll
    for (int k = 0; k < 16; ++k) {
      float a[4], b[4];
      #pragma unroll
      for (int x = 0; x < 4; ++x) a[x] = As[k][tm * 4 + x];
      #pragma unroll
      for (int x = 0; x < 4; ++x) b[x] = Bs[k][tn * 4 + x];
      #pragma unroll
      for (int x = 0; x < 4; ++x)
        #pragma unroll
        for (int y = 0; y < 4; ++y)
          acc[x][y] = fmaf(a[x], b[y], acc[x][y]);
    }
    __syncthreads();
  }
  #pragma unroll
  for (int x = 0; x < 4; ++x) {
    float4 v = make_float4(acc[x][0], acc[x][1], acc[x][2], acc[x][3]);
    *(float4*)(Hout + (size_t)(m0 + tm * 4 + x) * HF + n0 + tn * 4) = v;
  }
}

// ------------- Kernel 2: per-(b,n,h) dots with a_src/a_dst -----------------
__global__ __launch_bounds__(256) void attn_sd(const float* __restrict__ Hout,
                                               const float* __restrict__ a_src,
                                               const float* __restrict__ a_dst,
                                               float* __restrict__ Src,
                                               float* __restrict__ Dst) {
  const int m = blockIdx.x;          // b*N+n
  const int t = threadIdx.x;
  const int h = t >> 6, f = t & 63;
  const float v = Hout[(size_t)m * HF + t];
  float s = v * a_src[h * FO + f];
  float d = v * a_dst[h * FO + f];
  #pragma unroll
  for (int off = 32; off > 0; off >>= 1) {
    s += __shfl_down(s, off, 64);
    d += __shfl_down(d, off, 64);
  }
  if (f == 0) {
    const int b = m >> 11, n = m & (N - 1);
    Src[((b * H + h) << 11) + n] = s;
    Dst[((b * H + h) << 11) + n] = d;
  }
}

// ------------- Kernel 3: transpose Hout -> Ht bf16 [b][h][f][j] ------------
__global__ __launch_bounds__(256) void h2t(const float* __restrict__ Hout,
                                           unsigned short* __restrict__ Ht) {
  __shared__ float lds[64][65];
  const int bh = blockIdx.x >> 5;          // b*H + h
  const int j0 = (blockIdx.x & 31) * 64;
  const int b  = bh >> 2, h = bh & 3;
  const int t  = threadIdx.x;
  const int c4 = (t & 15) * 4;
  #pragma unroll
  for (int k = 0; k < 4; ++k) {
    const int jj = (t >> 4) + 16 * k;
    const float4 v = *(const float4*)(Hout + (size_t)(b * N + j0 + jj) * HF + h * FO + c4);
    lds[jj][c4 + 0] = v.x; lds[jj][c4 + 1] = v.y;
    lds[jj][c4 + 2] = v.z; lds[jj][c4 + 3] = v.w;
  }
  __syncthreads();
  const int j = t & 63;
  #pragma unroll
  for (int k = 0; k < 16; ++k) {
    const int f = (t >> 6) + 4 * k;
    Ht[((size_t)bh * FO + f) * N + j0 + j] = (unsigned short)f2bf(lds[j][f]);
  }
}

// ------------- Kernel 4: pack adj rows into bitmasks -----------------------
// packed[row][w] bit (j&63) = adj[row][64w+j] != 0. Little-endian bytes =>
// byte k of a row (viewed as uchar*) holds bits for j in [8k, 8k+8).
__global__ __launch_bounds__(256) void pack_adj(const float* __restrict__ adj,
                                                unsigned long long* __restrict__ packed) {
  const int row = blockIdx.x;
  const int w = threadIdx.x >> 6, l = threadIdx.x & 63;
  const float* ar = adj + (size_t)row * N;
  #pragma unroll
  for (int c = w; c < N / 64; c += 4) {
    unsigned long long m = __ballot(ar[c * 64 + l] != 0.f);
    if (l == 0) packed[(size_t)row * (N / 64) + c] = m;
  }
}

// ------------- Kernel 5: per-(b,h) global max of Dst -----------------------
__global__ __launch_bounds__(256) void dmax_k(const float* __restrict__ Dst,
                                              float* __restrict__ Dmax) {
  const int bh = blockIdx.x;
  const int t = threadIdx.x;
  float m = -INFINITY;
  #pragma unroll
  for (int j = t; j < N; j += 256) m = fmaxf(m, Dst[(bh << 11) + j]);
  #pragma unroll
  for (int off = 32; off > 0; off >>= 1) m = fmaxf(m, __shfl_xor(m, off, 64));
  __shared__ float sm[4];
  if ((t & 63) == 0) sm[t >> 6] = m;
  __syncthreads();
  if (t == 0) Dmax[bh] = fmaxf(fmaxf(sm[0], sm[1]), fmaxf(sm[2], sm[3]));
}

// ------------- Kernel 6: MFMA flash aggregation (v3) -----------------------
// Grid: B*(N/32) blocks, 512 threads (8 waves). Wave w: head h=w&3, j-half
// jh=w>>2. Each wave: 32-row i-tile (2 MFMA row-tiles), 4 f-tiles, half the
// j range in chunks of 32. Softmax shift m_i = leaky(s_i + Dmax[bh]) (valid
// upper bound; softmax is shift-invariant). Ones-column MFMA gives row sums.
// No barrier in the main loop -> compiler can pipeline global loads.
__global__ __launch_bounds__(512) void gat_mfma(const unsigned char* __restrict__ pb,
                                                const float* __restrict__ Src,
                                                const float* __restrict__ Dst,
                                                const float* __restrict__ Dmax,
                                                const unsigned short* __restrict__ Ht,
                                                float* __restrict__ out) {
  const int b    = blockIdx.x >> 6;          // N/32 = 64 i-tiles
  const int i0   = (blockIdx.x & 63) * 32;
  const int w    = threadIdx.x >> 6;
  const int lane = threadIdx.x & 63;
  const int h    = w & 3;
  const int jh   = w >> 2;
  const int bh   = b * H + h;
  const int fl   = lane & 15;
  const int kk   = (lane >> 4) * 8;

  const int row0 = i0 + fl;
  const int row1 = i0 + 16 + fl;
  const float dmx = Dmax[bh];
  const float s0 = Src[(bh << 11) + row0];
  const float s1 = Src[(bh << 11) + row1];
  const float t0 = s0 + dmx, m0 = fmaxf(t0, 0.2f * t0);
  const float t1 = s1 + dmx, m1 = fmaxf(t1, 0.2f * t1);
  const float* dz = Dst + (bh << 11);
  const unsigned char* pb0 = pb + (size_t)row0 * (N / 8);
  const unsigned char* pb1 = pb + (size_t)row1 * (N / 8);
  const unsigned short* ht0 = Ht + ((size_t)bh * FO + fl) * N;

  const short onebf = 0x3F80;  // bf16(1.0)
  short8 ones;
  #pragma unroll
  for (int jj = 0; jj < 8; ++jj) ones[jj] = onebf;

  const float4v zero = {0.f, 0.f, 0.f, 0.f};
  float4v acc[2][4];
  float4v accL[2];
  #pragma unroll
  for (int rt = 0; rt < 2; ++rt) {
    accL[rt] = zero;
    #pragma unroll
    for (int t = 0; t < 4; ++t) acc[rt][t] = zero;
  }

  const int jbeg = jh * (N / 2);
  for (int j0 = jbeg; j0 < jbeg + N / 2; j0 += 32) {
    const float4 d0 = *(const float4*)(dz + j0 + kk);
    const float4 d1 = *(const float4*)(dz + j0 + kk + 4);
    const unsigned int mk0 = pb0[(j0 + kk) >> 3];
    const unsigned int mk1 = pb1[(j0 + kk) >> 3];
    const float dv[8] = {d0.x, d0.y, d0.z, d0.w, d1.x, d1.y, d1.z, d1.w};
    short8 p0, p1;
    #pragma unroll
    for (int jj = 0; jj < 8; ++jj) {
      float sA = s0 + dv[jj]; sA = fmaxf(sA, 0.2f * sA);
      const float eA = __expf(sA - m0);
      p0[jj] = ((mk0 >> jj) & 1u) ? f2bf(eA) : (short)0;
      float sB = s1 + dv[jj]; sB = fmaxf(sB, 0.2f * sB);
      const float eB = __expf(sB - m1);
      p1[jj] = ((mk1 >> jj) & 1u) ? f2bf(eB) : (short)0;
    }
    const short8 b0 = *(const short8*)(ht0 + 0 * 16 * N + j0 + kk);
    const short8 b1 = *(const short8*)(ht0 + 1 * 16 * N + j0 + kk);
    const short8 b2 = *(const short8*)(ht0 + 2 * 16 * N + j0 + kk);
    const short8 b3 = *(const short8*)(ht0 + 3 * 16 * N + j0 + kk);
    acc[0][0] = __builtin_amdgcn_mfma_f32_16x16x32_bf16(p0, b0, acc[0][0], 0, 0, 0);
    acc[0][1] = __builtin_amdgcn_mfma_f32_16x16x32_bf16(p0, b1, acc[0][1], 0, 0, 0);
    acc[0][2] = __builtin_amdgcn_mfma_f32_16x16x32_bf16(p0, b2, acc[0][2], 0, 0, 0);
    acc[0][3] = __builtin_amdgcn_mfma_f32_16x16x32_bf16(p0, b3, acc[0][3], 0, 0, 0);
    accL[0]   = __builtin_amdgcn_mfma_f32_16x16x32_bf16(p0, ones, accL[0], 0, 0, 0);
    acc[1][0] = __builtin_amdgcn_mfma_f32_16x16x32_bf16(p1, b0, acc[1][0], 0, 0, 0);
    acc[1][1] = __builtin_amdgcn_mfma_f32_16x16x32_bf16(p1, b1, acc[1][1], 0, 0, 0);
    acc[1][2] = __builtin_amdgcn_mfma_f32_16x16x32_bf16(p1, b2, acc[1][2], 0, 0, 0);
    acc[1][3] = __builtin_amdgcn_mfma_f32_16x16x32_bf16(p1, b3, acc[1][3], 0, 0, 0);
    accL[1]   = __builtin_amdgcn_mfma_f32_16x16x32_bf16(p1, ones, accL[1], 0, 0, 0);
  }

  // combine the two j-halves through LDS
  __shared__ float4v parts[4][64][10];   // 40 KiB
  if (jh == 1) {
    #pragma unroll
    for (int rt = 0; rt < 2; ++rt) {
      #pragma unroll
      for (int t = 0; t < 4; ++t) parts[h][lane][rt * 5 + t] = acc[rt][t];
      parts[h][lane][rt * 5 + 4] = accL[rt];
    }
  }
  __syncthreads();
  if (jh == 0) {
    #pragma unroll
    for (int rt = 0; rt < 2; ++rt) {
      #pragma unroll
      for (int t = 0; t < 4; ++t) acc[rt][t] += parts[h][lane][rt * 5 + t];
      accL[rt] += parts[h][lane][rt * 5 + 4];
    }
    const int quad = lane >> 4;
    #pragma unroll
    for (int rt = 0; rt < 2; ++rt) {
      #pragma unroll
      for (int reg = 0; reg < 4; ++reg) {
        const int r = i0 + rt * 16 + quad * 4 + reg;
        const float invl = 1.f / accL[rt][reg];
        float* op = out + ((size_t)(b * N) + r) * HF + h * FO + fl;
        #pragma unroll
        for (int t = 0; t < 4; ++t) op[t * 16] = acc[rt][t][reg] * invl;
      }
    }
  }
}

extern "C" void kernel_launch(void* const* d_in, const int* in_sizes, int n_in,
                              void* d_out, int out_size, void* d_ws, size_t ws_size,
                              hipStream_t stream) {
  const float* x     = (const float*)d_in[0];
  const float* adj   = (const float*)d_in[1];
  const float* W     = (const float*)d_in[2];
  const float* a_src = (const float*)d_in[3];
  const float* a_dst = (const float*)d_in[4];
  float* out = (float*)d_out;

  float* Hout = (float*)d_ws;                        // 2M f32 = 8 MiB
  float* Src  = Hout + (size_t)M * HF;               // 32768 f32
  float* Dst  = Src + (size_t)B * H * N;             // 32768 f32
  float* Dmax = Dst + (size_t)B * H * N;             // 16 f32 (pad 64)
  unsigned short* Ht = (unsigned short*)(Dmax + 64); // 2M bf16 = 4 MiB
  unsigned long long* packed = (unsigned long long*)(Ht + (size_t)M * HF); // 512 KiB

  pack_adj<<<dim3(N), dim3(256), 0, stream>>>(adj, packed);
  gemm_xw<<<dim3((M / 64) * (HF / 64)), dim3(256), 0, stream>>>(x, W, Hout);
  attn_sd<<<dim3(M), dim3(256), 0, stream>>>(Hout, a_src, a_dst, Src, Dst);
  dmax_k<<<dim3(B * H), dim3(256), 0, stream>>>(Dst, Dmax);
  h2t<<<dim3(B * H * (N / 64)), dim3(256), 0, stream>>>(Hout, Ht);
  gat_mfma<<<dim3(B * (N / 32)), dim3(512), 0, stream>>>((const unsigned char*)packed,
                                                         Src, Dst, Dmax, Ht, out);
}

// Round 4
// 162.142 us; speedup vs baseline: 3.9334x; 1.0021x over previous
//
#include <hip/hip_runtime.h>
#include <hip/hip_bf16.h>
#include <math.h>

#define B 4
#define N 2048
#define FIN 256
#define H 4
#define FO 64
#define M (B*N)        // 8192 rows
#define HF (H*FO)      // 256 cols

typedef __attribute__((ext_vector_type(8))) short short8;   // 8 bf16 (4 VGPRs)
typedef __attribute__((ext_vector_type(4))) float float4v;  // MFMA C/D
typedef __attribute__((ext_vector_type(4))) int int4v;

#if __has_builtin(__builtin_amdgcn_exp2f)
#define EXP2(x) __builtin_amdgcn_exp2f(x)
#else
#define EXP2(x) exp2f(x)
#endif

// pack two f32 -> two bf16 (RNE) in one dword
static __device__ __forceinline__ unsigned int pk_rne(float a, float b) {
  unsigned int ua = __builtin_bit_cast(unsigned int, a);
  unsigned int ub = __builtin_bit_cast(unsigned int, b);
  ua += 0x7fffu + ((ua >> 16) & 1u);
  ub += 0x7fffu + ((ub >> 16) & 1u);
  return (ua >> 16) | (ub & 0xffff0000u);
}

// split x into hi (truncated bf16) + lo (truncated bf16 of remainder), packed pairs
static __device__ __forceinline__ void split_pair(float x0, float x1,
                                                  unsigned int& hi, unsigned int& lo) {
  unsigned int u0 = __builtin_bit_cast(unsigned int, x0);
  unsigned int u1 = __builtin_bit_cast(unsigned int, x1);
  hi = (u0 >> 16) | (u1 & 0xffff0000u);
  float h0 = __builtin_bit_cast(float, u0 & 0xffff0000u);
  float h1 = __builtin_bit_cast(float, u1 & 0xffff0000u);
  unsigned int l0 = __builtin_bit_cast(unsigned int, x0 - h0);
  unsigned int l1 = __builtin_bit_cast(unsigned int, x1 - h1);
  lo = (l0 >> 16) | (l1 & 0xffff0000u);
}

// ---- Kernel 1: W (FIN x HF fp32) -> Wt_hi/Wt_lo (HF x FIN bf16, transposed) ----
__global__ __launch_bounds__(256) void prep_w(const float* __restrict__ Wsrc,
                                              unsigned short* __restrict__ Wt_hi,
                                              unsigned short* __restrict__ Wt_lo) {
  __shared__ float lds[64][65];
  const int k0 = (blockIdx.x >> 2) * 64;
  const int n0 = (blockIdx.x & 3) * 64;
  const int t = threadIdx.x;
  const int c4 = (t & 15) * 4;
  #pragma unroll
  for (int rep = 0; rep < 4; ++rep) {
    const int kl = (t >> 4) + 16 * rep;
    const float4 v = *(const float4*)(Wsrc + (size_t)(k0 + kl) * HF + n0 + c4);
    lds[kl][c4 + 0] = v.x; lds[kl][c4 + 1] = v.y;
    lds[kl][c4 + 2] = v.z; lds[kl][c4 + 3] = v.w;
  }
  __syncthreads();
  const int n  = t >> 2;
  const int kc = (t & 3) * 16;
  unsigned int hv[8], lv[8];
  #pragma unroll
  for (int p = 0; p < 8; ++p)
    split_pair(lds[kc + 2 * p][n], lds[kc + 2 * p + 1][n], hv[p], lv[p]);
  unsigned short* dh = Wt_hi + (size_t)(n0 + n) * FIN + k0 + kc;
  unsigned short* dl = Wt_lo + (size_t)(n0 + n) * FIN + k0 + kc;
  ((uint4*)dh)[0] = make_uint4(hv[0], hv[1], hv[2], hv[3]);
  ((uint4*)dh)[1] = make_uint4(hv[4], hv[5], hv[6], hv[7]);
  ((uint4*)dl)[0] = make_uint4(lv[0], lv[1], lv[2], lv[3]);
  ((uint4*)dl)[1] = make_uint4(lv[4], lv[5], lv[6], lv[7]);
}

// ---- Kernel 2: fused h = x@W (bf16x2 MFMA) + Src/Dst dots + Ht bf16 write ----
// Grid: (M/64)*H blocks, 256 thr (4 waves). Wave w: rows m0=mb*64+w*16, head h.
__global__ __launch_bounds__(256) void gemm_fused(const float* __restrict__ X,
                                                  const unsigned short* __restrict__ Wt_hi,
                                                  const unsigned short* __restrict__ Wt_lo,
                                                  const float* __restrict__ a_src,
                                                  const float* __restrict__ a_dst,
                                                  float* __restrict__ Srcv,
                                                  float* __restrict__ Dstv,
                                                  unsigned short* __restrict__ Ht) {
  __shared__ unsigned int tlds[4][64][12];   // per-wave transpose buffer
  const int mb = blockIdx.x >> 2;
  const int h  = blockIdx.x & 3;
  const int w = threadIdx.x >> 6, lane = threadIdx.x & 63;
  const int fl = lane & 15, quad = lane >> 4, kk = quad * 8;
  const int m0 = mb * 64 + w * 16;
  const int r  = m0 + fl;
  const float* xr = X + (size_t)r * FIN;
  const unsigned short* whb = Wt_hi + (size_t)(h * FO + fl) * FIN;
  const unsigned short* wlb = Wt_lo + (size_t)(h * FO + fl) * FIN;

  const float4v zero = {0.f, 0.f, 0.f, 0.f};
  float4v acc[4] = {zero, zero, zero, zero};

  for (int k0 = 0; k0 < FIN; k0 += 32) {
    const float4 xa = *(const float4*)(xr + k0 + kk);
    const float4 xb = *(const float4*)(xr + k0 + kk + 4);
    const float xv[8] = {xa.x, xa.y, xa.z, xa.w, xb.x, xb.y, xb.z, xb.w};
    int hi[4], lo[4];
    #pragma unroll
    for (int p = 0; p < 4; ++p) {
      unsigned int hp, lp;
      split_pair(xv[2 * p], xv[2 * p + 1], hp, lp);
      hi[p] = (int)hp; lo[p] = (int)lp;
    }
    const short8 Ahi = __builtin_bit_cast(short8, (int4v){hi[0], hi[1], hi[2], hi[3]});
    const short8 Alo = __builtin_bit_cast(short8, (int4v){lo[0], lo[1], lo[2], lo[3]});
    #pragma unroll
    for (int t = 0; t < 4; ++t) {
      const short8 Bhi = *(const short8*)(whb + t * 16 * FIN + k0 + kk);
      const short8 Blo = *(const short8*)(wlb + t * 16 * FIN + k0 + kk);
      acc[t] = __builtin_amdgcn_mfma_f32_16x16x32_bf16(Ahi, Bhi, acc[t], 0, 0, 0);
      acc[t] = __builtin_amdgcn_mfma_f32_16x16x32_bf16(Alo, Bhi, acc[t], 0, 0, 0);
      acc[t] = __builtin_amdgcn_mfma_f32_16x16x32_bf16(Ahi, Blo, acc[t], 0, 0, 0);
    }
  }

  // ---- epilogue: Src/Dst dots (fp32-exact from accs) ----
  const int bb  = m0 >> 11;          // batch
  const int n0w = m0 & (N - 1);      // node base of this wave tile
  const int bh  = bb * H + h;
  float as[4], ad[4];
  #pragma unroll
  for (int t = 0; t < 4; ++t) {
    as[t] = a_src[h * FO + t * 16 + fl];
    ad[t] = a_dst[h * FO + t * 16 + fl];
  }
  #pragma unroll
  for (int reg = 0; reg < 4; ++reg) {
    float sv = 0.f, dv = 0.f;
    #pragma unroll
    for (int t = 0; t < 4; ++t) {
      sv = fmaf(acc[t][reg], as[t], sv);
      dv = fmaf(acc[t][reg], ad[t], dv);
    }
    #pragma unroll
    for (int off = 1; off <= 8; off <<= 1) {
      sv += __shfl_xor(sv, off, 64);
      dv += __shfl_xor(dv, off, 64);
    }
    if (fl == 0) {
      const int node = n0w + quad * 4 + reg;
      Srcv[(bh << 11) + node] = sv;
      Dstv[(bh << 11) + node] = dv;
    }
  }

  // ---- epilogue: bf16 Ht[bh][f][n] via in-wave LDS transpose ----
  #pragma unroll
  for (int t = 0; t < 4; ++t) {
    #pragma unroll
    for (int rp = 0; rp < 2; ++rp)
      tlds[w][t * 16 + fl][quad * 2 + rp] = pk_rne(acc[t][2 * rp], acc[t][2 * rp + 1]);
  }
  // same wave wrote what it reads; lgkmcnt handled by compiler
  const uint4 v0 = *(const uint4*)&tlds[w][lane][0];
  const uint4 v1 = *(const uint4*)&tlds[w][lane][4];
  unsigned short* dst = Ht + ((size_t)bh * FO + lane) * N + n0w;
  ((uint4*)dst)[0] = v0;
  ((uint4*)dst)[1] = v1;
}

// ---- Kernel 3: per-(b,h) global max of Dst ----
__global__ __launch_bounds__(256) void dmax_k(const float* __restrict__ Dst,
                                              float* __restrict__ Dmax) {
  const int bh = blockIdx.x;
  const int t = threadIdx.x;
  float m = -INFINITY;
  #pragma unroll
  for (int j = t; j < N; j += 256) m = fmaxf(m, Dst[(bh << 11) + j]);
  #pragma unroll
  for (int off = 32; off > 0; off >>= 1) m = fmaxf(m, __shfl_xor(m, off, 64));
  __shared__ float sm[4];
  if ((t & 63) == 0) sm[t >> 6] = m;
  __syncthreads();
  if (t == 0) Dmax[bh] = fmaxf(fmaxf(sm[0], sm[1]), fmaxf(sm[2], sm[3]));
}

// ---- Kernel 4: MFMA flash aggregation (v4) ----
// Grid: B*(N/32) = 256 blocks, 1024 thr (16 waves). Wave w: head h=w&3,
// j-quarter q=w>>2. 32-row i-tile (2 MFMA row-tiles). Mask applied by
// multiplying with raw adj (exact 0/1 floats). exp2-domain scores.
// LDS tree-combine of the 4 quarters, then q=0 normalizes and writes.
__global__ __launch_bounds__(1024) void gat_mfma(const float* __restrict__ adj,
                                                 const float* __restrict__ Src,
                                                 const float* __restrict__ Dst,
                                                 const float* __restrict__ Dmax,
                                                 const unsigned short* __restrict__ Ht,
                                                 float* __restrict__ out) {
  const int b    = blockIdx.x >> 6;
  const int i0   = (blockIdx.x & 63) * 32;
  const int w    = threadIdx.x >> 6;
  const int lane = threadIdx.x & 63;
  const int h    = w & 3;
  const int q    = w >> 2;
  const int bh   = b * H + h;
  const int fl   = lane & 15;
  const int kk   = (lane >> 4) * 8;
  const float L2E = 1.4426950408889634f;

  const int row0 = i0 + fl;
  const int row1 = i0 + 16 + fl;
  const float dmx = Dmax[bh];
  const float s0 = Src[(bh << 11) + row0];
  const float s1 = Src[(bh << 11) + row1];
  const float u0 = s0 + dmx, m0L = fmaxf(u0, 0.2f * u0) * L2E;
  const float u1 = s1 + dmx, m1L = fmaxf(u1, 0.2f * u1) * L2E;
  const float s0L = s0 * L2E, s1L = s1 * L2E;
  const float* dz   = Dst + (bh << 11);
  const float* ar0  = adj + (size_t)row0 * N;
  const float* ar1  = adj + (size_t)row1 * N;
  const unsigned short* ht0 = Ht + ((size_t)bh * FO + fl) * N;

  const short onebf = 0x3F80;
  short8 ones;
  #pragma unroll
  for (int jj = 0; jj < 8; ++jj) ones[jj] = onebf;

  const float4v zero = {0.f, 0.f, 0.f, 0.f};
  float4v acc[2][4];
  float4v accL[2];
  #pragma unroll
  for (int rt = 0; rt < 2; ++rt) {
    accL[rt] = zero;
    #pragma unroll
    for (int t = 0; t < 4; ++t) acc[rt][t] = zero;
  }

  const int jbeg = q * (N / 4);
  for (int j0 = jbeg; j0 < jbeg + N / 4; j0 += 32) {
    const float4 d0  = *(const float4*)(dz + j0 + kk);
    const float4 d1  = *(const float4*)(dz + j0 + kk + 4);
    const float4 a00 = *(const float4*)(ar0 + j0 + kk);
    const float4 a01 = *(const float4*)(ar0 + j0 + kk + 4);
    const float4 a10 = *(const float4*)(ar1 + j0 + kk);
    const float4 a11 = *(const float4*)(ar1 + j0 + kk + 4);
    const float dL[8]  = {d0.x * L2E, d0.y * L2E, d0.z * L2E, d0.w * L2E,
                          d1.x * L2E, d1.y * L2E, d1.z * L2E, d1.w * L2E};
    const float av0[8] = {a00.x, a00.y, a00.z, a00.w, a01.x, a01.y, a01.z, a01.w};
    const float av1[8] = {a10.x, a10.y, a10.z, a10.w, a11.x, a11.y, a11.z, a11.w};
    int p0i[4], p1i[4];
    #pragma unroll
    for (int p = 0; p < 4; ++p) {
      const int e0 = 2 * p, e1 = 2 * p + 1;
      float ua = s0L + dL[e0];
      float ta = fmaxf(ua - m0L, fmaf(0.2f, ua, -m0L));
      float ea = EXP2(ta) * av0[e0];
      float ub = s0L + dL[e1];
      float tb = fmaxf(ub - m0L, fmaf(0.2f, ub, -m0L));
      float eb = EXP2(tb) * av0[e1];
      p0i[p] = (int)pk_rne(ea, eb);
      float uc = s1L + dL[e0];
      float tc = fmaxf(uc - m1L, fmaf(0.2f, uc, -m1L));
      float ec = EXP2(tc) * av1[e0];
      float ud = s1L + dL[e1];
      float td = fmaxf(ud - m1L, fmaf(0.2f, ud, -m1L));
      float ed = EXP2(td) * av1[e1];
      p1i[p] = (int)pk_rne(ec, ed);
    }
    const short8 p0 = __builtin_bit_cast(short8, (int4v){p0i[0], p0i[1], p0i[2], p0i[3]});
    const short8 p1 = __builtin_bit_cast(short8, (int4v){p1i[0], p1i[1], p1i[2], p1i[3]});
    const short8 b0 = *(const short8*)(ht0 + 0 * 16 * N + j0 + kk);
    const short8 b1 = *(const short8*)(ht0 + 1 * 16 * N + j0 + kk);
    const short8 b2 = *(const short8*)(ht0 + 2 * 16 * N + j0 + kk);
    const short8 b3 = *(const short8*)(ht0 + 3 * 16 * N + j0 + kk);
    acc[0][0] = __builtin_amdgcn_mfma_f32_16x16x32_bf16(p0, b0, acc[0][0], 0, 0, 0);
    acc[0][1] = __builtin_amdgcn_mfma_f32_16x16x32_bf16(p0, b1, acc[0][1], 0, 0, 0);
    acc[0][2] = __builtin_amdgcn_mfma_f32_16x16x32_bf16(p0, b2, acc[0][2], 0, 0, 0);
    acc[0][3] = __builtin_amdgcn_mfma_f32_16x16x32_bf16(p0, b3, acc[0][3], 0, 0, 0);
    accL[0]   = __builtin_amdgcn_mfma_f32_16x16x32_bf16(p0, ones, accL[0], 0, 0, 0);
    acc[1][0] = __builtin_amdgcn_mfma_f32_16x16x32_bf16(p1, b0, acc[1][0], 0, 0, 0);
    acc[1][1] = __builtin_amdgcn_mfma_f32_16x16x32_bf16(p1, b1, acc[1][1], 0, 0, 0);
    acc[1][2] = __builtin_amdgcn_mfma_f32_16x16x32_bf16(p1, b2, acc[1][2], 0, 0, 0);
    acc[1][3] = __builtin_amdgcn_mfma_f32_16x16x32_bf16(p1, b3, acc[1][3], 0, 0, 0);
    accL[1]   = __builtin_amdgcn_mfma_f32_16x16x32_bf16(p1, ones, accL[1], 0, 0, 0);
  }

  // ---- combine the 4 j-quarters: q3 -> q2 -> q1 -> q0 ----
  __shared__ float4v parts[4][64][11];   // 44 KiB (11 = pad for bank spread)
  for (int r = 3; r >= 1; --r) {
    if (q == r) {
      #pragma unroll
      for (int rt = 0; rt < 2; ++rt) {
        #pragma unroll
        for (int t = 0; t < 4; ++t) parts[h][lane][rt * 5 + t] = acc[rt][t];
        parts[h][lane][rt * 5 + 4] = accL[rt];
      }
    }
    __syncthreads();
    if (q == r - 1) {
      #pragma unroll
      for (int rt = 0; rt < 2; ++rt) {
        #pragma unroll
        for (int t = 0; t < 4; ++t) acc[rt][t] += parts[h][lane][rt * 5 + t];
        accL[rt] += parts[h][lane][rt * 5 + 4];
      }
    }
    __syncthreads();
  }

  if (q == 0) {
    const int quad = lane >> 4;
    #pragma unroll
    for (int rt = 0; rt < 2; ++rt) {
      #pragma unroll
      for (int reg = 0; reg < 4; ++reg) {
        const int r = i0 + rt * 16 + quad * 4 + reg;
        const float invl = 1.f / accL[rt][reg];
        float* op = out + ((size_t)(b * N) + r) * HF + h * FO + fl;
        #pragma unroll
        for (int t = 0; t < 4; ++t) op[t * 16] = acc[rt][t][reg] * invl;
      }
    }
  }
}

extern "C" void kernel_launch(void* const* d_in, const int* in_sizes, int n_in,
                              void* d_out, int out_size, void* d_ws, size_t ws_size,
                              hipStream_t stream) {
  const float* x     = (const float*)d_in[0];
  const float* adj   = (const float*)d_in[1];
  const float* W     = (const float*)d_in[2];
  const float* a_src = (const float*)d_in[3];
  const float* a_dst = (const float*)d_in[4];
  float* out = (float*)d_out;

  float* Srcv = (float*)d_ws;                         // B*H*N f32
  float* Dstv = Srcv + (size_t)B * H * N;             // B*H*N f32
  float* Dmax = Dstv + (size_t)B * H * N;             // 16 f32 (pad 64)
  unsigned short* Wth = (unsigned short*)(Dmax + 64); // HF*FIN bf16
  unsigned short* Wtl = Wth + (size_t)HF * FIN;       // HF*FIN bf16
  unsigned short* Ht  = Wtl + (size_t)HF * FIN;       // M*HF bf16 = 4 MiB

  prep_w<<<dim3(16), dim3(256), 0, stream>>>(W, Wth, Wtl);
  gemm_fused<<<dim3((M / 64) * H), dim3(256), 0, stream>>>(x, Wth, Wtl, a_src, a_dst,
                                                           Srcv, Dstv, Ht);
  dmax_k<<<dim3(B * H), dim3(256), 0, stream>>>(Dstv, Dmax);
  gat_mfma<<<dim3(B * (N / 32)), dim3(1024), 0, stream>>>(adj, Srcv, Dstv, Dmax, Ht, out);
}

// Round 6
// 159.925 us; speedup vs baseline: 3.9879x; 1.0139x over previous
//
#include <hip/hip_runtime.h>
#include <hip/hip_bf16.h>
#include <math.h>

#define B 4
#define N 2048
#define FIN 256
#define H 4
#define FO 64
#define M (B*N)        // 8192 rows
#define HF (H*FO)      // 256 cols

typedef __attribute__((ext_vector_type(8))) short short8;   // 8 bf16 (4 VGPRs)
typedef __attribute__((ext_vector_type(4))) float float4v;  // MFMA C/D
typedef __attribute__((ext_vector_type(4))) int int4v;

#if __has_builtin(__builtin_amdgcn_exp2f)
#define EXP2(x) __builtin_amdgcn_exp2f(x)
#else
#define EXP2(x) exp2f(x)
#endif

// pack two f32 -> two bf16 (RNE) in one dword
static __device__ __forceinline__ unsigned int pk_rne(float a, float b) {
  unsigned int ua = __builtin_bit_cast(unsigned int, a);
  unsigned int ub = __builtin_bit_cast(unsigned int, b);
  ua += 0x7fffu + ((ua >> 16) & 1u);
  ub += 0x7fffu + ((ub >> 16) & 1u);
  return (ua >> 16) | (ub & 0xffff0000u);
}

// pack two f32 -> two bf16 (truncate) in one dword: 1 v_perm_b32
static __device__ __forceinline__ unsigned int pk_trunc(float a, float b) {
#if __has_builtin(__builtin_amdgcn_perm)
  return __builtin_amdgcn_perm(__builtin_bit_cast(unsigned int, b),
                               __builtin_bit_cast(unsigned int, a), 0x07060302u);
#else
  return (__builtin_bit_cast(unsigned int, a) >> 16) |
         (__builtin_bit_cast(unsigned int, b) & 0xffff0000u);
#endif
}

// split x into hi (truncated bf16) + lo (truncated bf16 of remainder), packed pairs
static __device__ __forceinline__ void split_pair(float x0, float x1,
                                                  unsigned int& hi, unsigned int& lo) {
  unsigned int u0 = __builtin_bit_cast(unsigned int, x0);
  unsigned int u1 = __builtin_bit_cast(unsigned int, x1);
  hi = (u0 >> 16) | (u1 & 0xffff0000u);
  float h0 = __builtin_bit_cast(float, u0 & 0xffff0000u);
  float h1 = __builtin_bit_cast(float, u1 & 0xffff0000u);
  unsigned int l0 = __builtin_bit_cast(unsigned int, x0 - h0);
  unsigned int l1 = __builtin_bit_cast(unsigned int, x1 - h1);
  lo = (l0 >> 16) | (l1 & 0xffff0000u);
}

// monotone float<->uint encoding for atomicMax
static __device__ __forceinline__ unsigned int fenc(float f) {
  unsigned int b = __builtin_bit_cast(unsigned int, f);
  return (b & 0x80000000u) ? ~b : (b | 0x80000000u);
}
static __device__ __forceinline__ float fdec(unsigned int e) {
  unsigned int b = (e & 0x80000000u) ? (e & 0x7fffffffu) : ~e;
  return __builtin_bit_cast(float, b);
}

// ---- Kernel 1: W -> Wt_hi/Wt_lo (HF x FIN bf16, transposed); zero DmaxEnc ----
__global__ __launch_bounds__(256) void prep_w(const float* __restrict__ Wsrc,
                                              unsigned short* __restrict__ Wt_hi,
                                              unsigned short* __restrict__ Wt_lo,
                                              unsigned int* __restrict__ DmaxEnc) {
  if (blockIdx.x == 0 && threadIdx.x < 16) DmaxEnc[threadIdx.x] = 0u;
  __shared__ float lds[64][65];
  const int k0 = (blockIdx.x >> 2) * 64;
  const int n0 = (blockIdx.x & 3) * 64;
  const int t = threadIdx.x;
  const int c4 = (t & 15) * 4;
  #pragma unroll
  for (int rep = 0; rep < 4; ++rep) {
    const int kl = (t >> 4) + 16 * rep;
    const float4 v = *(const float4*)(Wsrc + (size_t)(k0 + kl) * HF + n0 + c4);
    lds[kl][c4 + 0] = v.x; lds[kl][c4 + 1] = v.y;
    lds[kl][c4 + 2] = v.z; lds[kl][c4 + 3] = v.w;
  }
  __syncthreads();
  const int n  = t >> 2;
  const int kc = (t & 3) * 16;
  unsigned int hv[8], lv[8];
  #pragma unroll
  for (int p = 0; p < 8; ++p)
    split_pair(lds[kc + 2 * p][n], lds[kc + 2 * p + 1][n], hv[p], lv[p]);
  unsigned short* dh = Wt_hi + (size_t)(n0 + n) * FIN + k0 + kc;
  unsigned short* dl = Wt_lo + (size_t)(n0 + n) * FIN + k0 + kc;
  ((uint4*)dh)[0] = make_uint4(hv[0], hv[1], hv[2], hv[3]);
  ((uint4*)dh)[1] = make_uint4(hv[4], hv[5], hv[6], hv[7]);
  ((uint4*)dl)[0] = make_uint4(lv[0], lv[1], lv[2], lv[3]);
  ((uint4*)dl)[1] = make_uint4(lv[4], lv[5], lv[6], lv[7]);
}

// ---- Kernel 2: pack adj rows into bitmasks (bit j&7 of byte j>>3) ----
__global__ __launch_bounds__(256) void pack_adj(const float* __restrict__ adj,
                                                unsigned long long* __restrict__ packed) {
  const int row = blockIdx.x;
  const int w = threadIdx.x >> 6, l = threadIdx.x & 63;
  const float* ar = adj + (size_t)row * N;
  for (int c = w; c < N / 64; c += 4) {
    unsigned long long m = __ballot(ar[c * 64 + l] != 0.f);
    if (l == 0) packed[(size_t)row * (N / 64) + c] = m;
  }
}

// ---- Kernel 3: fused h=x@W (bf16x2 MFMA) + Src dot + E-pair + dmax + Ht ----
// Grid: (M/64)*H blocks, 256 thr (4 waves). Wave w: rows m0=mb*64+w*16, head h.
__global__ __launch_bounds__(256) void gemm_fused(const float* __restrict__ X,
                                                  const unsigned short* __restrict__ Wt_hi,
                                                  const unsigned short* __restrict__ Wt_lo,
                                                  const float* __restrict__ a_src,
                                                  const float* __restrict__ a_dst,
                                                  float* __restrict__ Srcv,
                                                  float2* __restrict__ Epair,
                                                  unsigned int* __restrict__ DmaxEnc,
                                                  unsigned short* __restrict__ Ht) {
  __shared__ unsigned short sh[64][72];   // [f][node] bf16 tile (pitch 72 -> 16B align)
  __shared__ float smax[4];
  const int mb = blockIdx.x >> 2;
  const int h  = blockIdx.x & 3;
  const int w = threadIdx.x >> 6, lane = threadIdx.x & 63;
  const int fl = lane & 15, quad = lane >> 4, kk = quad * 8;
  const int m0 = mb * 64 + w * 16;
  const float* xr = X + (size_t)(m0 + fl) * FIN;
  const unsigned short* whb = Wt_hi + (size_t)(h * FO + fl) * FIN;
  const unsigned short* wlb = Wt_lo + (size_t)(h * FO + fl) * FIN;
  const float L2E = 1.4426950408889634f;

  const float4v zero = {0.f, 0.f, 0.f, 0.f};
  float4v acc[4] = {zero, zero, zero, zero};

  for (int k0 = 0; k0 < FIN; k0 += 32) {
    const float4 xa = *(const float4*)(xr + k0 + kk);
    const float4 xb = *(const float4*)(xr + k0 + kk + 4);
    const float xv[8] = {xa.x, xa.y, xa.z, xa.w, xb.x, xb.y, xb.z, xb.w};
    int hi[4], lo[4];
    #pragma unroll
    for (int p = 0; p < 4; ++p) {
      unsigned int hp, lp;
      split_pair(xv[2 * p], xv[2 * p + 1], hp, lp);
      hi[p] = (int)hp; lo[p] = (int)lp;
    }
    const short8 Ahi = __builtin_bit_cast(short8, (int4v){hi[0], hi[1], hi[2], hi[3]});
    const short8 Alo = __builtin_bit_cast(short8, (int4v){lo[0], lo[1], lo[2], lo[3]});
    #pragma unroll
    for (int t = 0; t < 4; ++t) {
      const short8 Bhi = *(const short8*)(whb + t * 16 * FIN + k0 + kk);
      const short8 Blo = *(const short8*)(wlb + t * 16 * FIN + k0 + kk);
      acc[t] = __builtin_amdgcn_mfma_f32_16x16x32_bf16(Ahi, Bhi, acc[t], 0, 0, 0);
      acc[t] = __builtin_amdgcn_mfma_f32_16x16x32_bf16(Alo, Bhi, acc[t], 0, 0, 0);
      acc[t] = __builtin_amdgcn_mfma_f32_16x16x32_bf16(Ahi, Blo, acc[t], 0, 0, 0);
    }
  }

  // ---- Src dot, E-pair, wave max of d ----
  const int bb  = (mb * 64) >> 11;     // batch
  const int n0w = (mb * 64) & (N - 1); // block node base within batch
  const int bh  = bb * H + h;
  float as[4], ad[4];
  #pragma unroll
  for (int t = 0; t < 4; ++t) {
    as[t] = a_src[h * FO + t * 16 + fl];
    ad[t] = a_dst[h * FO + t * 16 + fl];
  }
  float wmax = -INFINITY;
  #pragma unroll
  for (int reg = 0; reg < 4; ++reg) {
    float sv = 0.f, dv = 0.f;
    #pragma unroll
    for (int t = 0; t < 4; ++t) {
      sv = fmaf(acc[t][reg], as[t], sv);
      dv = fmaf(acc[t][reg], ad[t], dv);
    }
    #pragma unroll
    for (int off = 1; off <= 8; off <<= 1) {
      sv += __shfl_xor(sv, off, 64);
      dv += __shfl_xor(dv, off, 64);
    }
    wmax = fmaxf(wmax, dv);
    if (fl == 0) {
      const int node = n0w + w * 16 + quad * 4 + reg;
      Srcv[(bh << 11) + node] = sv;
      float2 e;
      e.x = EXP2(dv * L2E);            // exp(d)
      e.y = EXP2(dv * (0.2f * L2E));   // exp(0.2 d)
      Epair[(bh << 11) + node] = e;
    }
  }
  wmax = fmaxf(wmax, __shfl_xor(wmax, 16, 64));
  wmax = fmaxf(wmax, __shfl_xor(wmax, 32, 64));
  if (lane == 0) smax[w] = wmax;

  // ---- stage bf16 tile: sh[f][node] ----
  #pragma unroll
  for (int t = 0; t < 4; ++t) {
    const int nl = w * 16 + quad * 4;
    *(unsigned int*)&sh[t * 16 + fl][nl]     = pk_rne(acc[t][0], acc[t][1]);
    *(unsigned int*)&sh[t * 16 + fl][nl + 2] = pk_rne(acc[t][2], acc[t][3]);
  }
  __syncthreads();
  if (threadIdx.x == 0) {
    const float bmax = fmaxf(fmaxf(smax[0], smax[1]), fmaxf(smax[2], smax[3]));
    atomicMax(DmaxEnc + bh, fenc(bmax));
  }
  // ---- coalesced Ht write: full 128B lines (node base = n0w, NOT mb*64) ----
  const int f = threadIdx.x >> 2, seg = threadIdx.x & 3;
  unsigned short* dsth = Ht + ((size_t)bh * FO + f) * N + n0w + seg * 16;
  const uint4* srcp = (const uint4*)&sh[f][seg * 16];
  ((uint4*)dsth)[0] = srcp[0];
  ((uint4*)dsth)[1] = srcp[1];
}

// ---- Kernel 4: MFMA flash aggregation (v5: no-exp inner loop, packed adj) ----
// Grid: B*(N/32)=256 blocks, 1024 thr (16 waves). Wave: head h=w&3, quarter q=w>>2.
// p_ij = sel ? c1_i*E1_j : c2_i*E2_j, sel = (E1_j > t_i), zeroed by adj bit.
__global__ __launch_bounds__(1024) void gat_mfma(const unsigned char* __restrict__ pb,
                                                 const float* __restrict__ Src,
                                                 const float2* __restrict__ Epair,
                                                 const unsigned int* __restrict__ DmaxEnc,
                                                 const unsigned short* __restrict__ Ht,
                                                 float* __restrict__ out) {
  const int b    = blockIdx.x >> 6;
  const int i0   = (blockIdx.x & 63) * 32;
  const int w    = threadIdx.x >> 6;
  const int lane = threadIdx.x & 63;
  const int h    = w & 3;
  const int q    = w >> 2;
  const int bh   = b * H + h;
  const int fl   = lane & 15;
  const int kk   = (lane >> 4) * 8;
  const float L2E = 1.4426950408889634f;

  const int row0 = i0 + fl;
  const int row1 = i0 + 16 + fl;
  const float dmx = fdec(DmaxEnc[bh]);
  const float s0 = Src[(bh << 11) + row0];
  const float s1 = Src[(bh << 11) + row1];
  const float u0 = s0 + dmx, m0 = fmaxf(u0, 0.2f * u0);
  const float u1 = s1 + dmx, m1 = fmaxf(u1, 0.2f * u1);
  const float c1a = EXP2((s0 - m0) * L2E), c2a = EXP2((0.2f * s0 - m0) * L2E);
  const float c1b = EXP2((s1 - m1) * L2E), c2b = EXP2((0.2f * s1 - m1) * L2E);
  const float ta = EXP2(-s0 * L2E), tb = EXP2(-s1 * L2E);
  const float* ep = (const float*)(Epair + (bh << 11));
  const unsigned char* pb0 = pb + (size_t)row0 * (N / 8);
  const unsigned char* pb1 = pb + (size_t)row1 * (N / 8);
  const unsigned short* ht0 = Ht + ((size_t)bh * FO + fl) * N;

  const short onebf = 0x3F80;
  short8 ones;
  #pragma unroll
  for (int jj = 0; jj < 8; ++jj) ones[jj] = onebf;

  const float4v zero = {0.f, 0.f, 0.f, 0.f};
  float4v acc[2][4];
  float4v accL[2];
  #pragma unroll
  for (int rt = 0; rt < 2; ++rt) {
    accL[rt] = zero;
    #pragma unroll
    for (int t = 0; t < 4; ++t) acc[rt][t] = zero;
  }

  const int jbeg = q * (N / 4);
  #pragma unroll 2
  for (int j0 = jbeg; j0 < jbeg + N / 4; j0 += 32) {
    const float4 q0 = *(const float4*)(ep + 2 * (j0 + kk) + 0);
    const float4 q1 = *(const float4*)(ep + 2 * (j0 + kk) + 4);
    const float4 q2 = *(const float4*)(ep + 2 * (j0 + kk) + 8);
    const float4 q3 = *(const float4*)(ep + 2 * (j0 + kk) + 12);
    const unsigned int mk0 = pb0[(j0 + kk) >> 3];
    const unsigned int mk1 = pb1[(j0 + kk) >> 3];
    const float E1v[8] = {q0.x, q0.z, q1.x, q1.z, q2.x, q2.z, q3.x, q3.z};
    const float E2v[8] = {q0.y, q0.w, q1.y, q1.w, q2.y, q2.w, q3.y, q3.w};
    int p0i[4], p1i[4];
    #pragma unroll
    for (int p = 0; p < 4; ++p) {
      const int e0 = 2 * p, e1 = 2 * p + 1;
      const bool sa0 = E1v[e0] > ta;
      float va0 = (sa0 ? c1a : c2a) * (sa0 ? E1v[e0] : E2v[e0]);
      va0 = ((mk0 >> e0) & 1u) ? va0 : 0.f;
      const bool sa1 = E1v[e1] > ta;
      float va1 = (sa1 ? c1a : c2a) * (sa1 ? E1v[e1] : E2v[e1]);
      va1 = ((mk0 >> e1) & 1u) ? va1 : 0.f;
      p0i[p] = (int)pk_trunc(va0, va1);
      const bool sb0 = E1v[e0] > tb;
      float vb0 = (sb0 ? c1b : c2b) * (sb0 ? E1v[e0] : E2v[e0]);
      vb0 = ((mk1 >> e0) & 1u) ? vb0 : 0.f;
      const bool sb1 = E1v[e1] > tb;
      float vb1 = (sb1 ? c1b : c2b) * (sb1 ? E1v[e1] : E2v[e1]);
      vb1 = ((mk1 >> e1) & 1u) ? vb1 : 0.f;
      p1i[p] = (int)pk_trunc(vb0, vb1);
    }
    const short8 p0 = __builtin_bit_cast(short8, (int4v){p0i[0], p0i[1], p0i[2], p0i[3]});
    const short8 p1 = __builtin_bit_cast(short8, (int4v){p1i[0], p1i[1], p1i[2], p1i[3]});
    const short8 b0 = *(const short8*)(ht0 + 0 * 16 * N + j0 + kk);
    const short8 b1 = *(const short8*)(ht0 + 1 * 16 * N + j0 + kk);
    const short8 b2 = *(const short8*)(ht0 + 2 * 16 * N + j0 + kk);
    const short8 b3 = *(const short8*)(ht0 + 3 * 16 * N + j0 + kk);
    acc[0][0] = __builtin_amdgcn_mfma_f32_16x16x32_bf16(p0, b0, acc[0][0], 0, 0, 0);
    acc[0][1] = __builtin_amdgcn_mfma_f32_16x16x32_bf16(p0, b1, acc[0][1], 0, 0, 0);
    acc[0][2] = __builtin_amdgcn_mfma_f32_16x16x32_bf16(p0, b2, acc[0][2], 0, 0, 0);
    acc[0][3] = __builtin_amdgcn_mfma_f32_16x16x32_bf16(p0, b3, acc[0][3], 0, 0, 0);
    accL[0]   = __builtin_amdgcn_mfma_f32_16x16x32_bf16(p0, ones, accL[0], 0, 0, 0);
    acc[1][0] = __builtin_amdgcn_mfma_f32_16x16x32_bf16(p1, b0, acc[1][0], 0, 0, 0);
    acc[1][1] = __builtin_amdgcn_mfma_f32_16x16x32_bf16(p1, b1, acc[1][1], 0, 0, 0);
    acc[1][2] = __builtin_amdgcn_mfma_f32_16x16x32_bf16(p1, b2, acc[1][2], 0, 0, 0);
    acc[1][3] = __builtin_amdgcn_mfma_f32_16x16x32_bf16(p1, b3, acc[1][3], 0, 0, 0);
    accL[1]   = __builtin_amdgcn_mfma_f32_16x16x32_bf16(p1, ones, accL[1], 0, 0, 0);
  }

  // ---- combine the 4 j-quarters: q3 -> q2 -> q1 -> q0 ----
  __shared__ float4v parts[4][64][11];
  for (int r = 3; r >= 1; --r) {
    if (q == r) {
      #pragma unroll
      for (int rt = 0; rt < 2; ++rt) {
        #pragma unroll
        for (int t = 0; t < 4; ++t) parts[h][lane][rt * 5 + t] = acc[rt][t];
        parts[h][lane][rt * 5 + 4] = accL[rt];
      }
    }
    __syncthreads();
    if (q == r - 1) {
      #pragma unroll
      for (int rt = 0; rt < 2; ++rt) {
        #pragma unroll
        for (int t = 0; t < 4; ++t) acc[rt][t] += parts[h][lane][rt * 5 + t];
        accL[rt] += parts[h][lane][rt * 5 + 4];
      }
    }
    __syncthreads();
  }

  if (q == 0) {
    const int quad = lane >> 4;
    #pragma unroll
    for (int rt = 0; rt < 2; ++rt) {
      #pragma unroll
      for (int reg = 0; reg < 4; ++reg) {
        const int r = i0 + rt * 16 + quad * 4 + reg;
        const float invl = 1.f / accL[rt][reg];
        float* op = out + ((size_t)(b * N) + r) * HF + h * FO + fl;
        #pragma unroll
        for (int t = 0; t < 4; ++t) op[t * 16] = acc[rt][t][reg] * invl;
      }
    }
  }
}

extern "C" void kernel_launch(void* const* d_in, const int* in_sizes, int n_in,
                              void* d_out, int out_size, void* d_ws, size_t ws_size,
                              hipStream_t stream) {
  const float* x     = (const float*)d_in[0];
  const float* adj   = (const float*)d_in[1];
  const float* W     = (const float*)d_in[2];
  const float* a_src = (const float*)d_in[3];
  const float* a_dst = (const float*)d_in[4];
  float* out = (float*)d_out;

  char* p = (char*)d_ws;
  float* Srcv = (float*)p;                 p += (size_t)B * H * N * 4;   // 128 KiB
  float2* Epair = (float2*)p;              p += (size_t)B * H * N * 8;   // 256 KiB
  unsigned int* DmaxEnc = (unsigned int*)p; p += 256;
  unsigned short* Wth = (unsigned short*)p; p += (size_t)HF * FIN * 2;   // 128 KiB
  unsigned short* Wtl = (unsigned short*)p; p += (size_t)HF * FIN * 2;   // 128 KiB
  unsigned short* Ht  = (unsigned short*)p; p += (size_t)M * HF * 2;     // 4 MiB
  unsigned long long* packed = (unsigned long long*)p;                   // 512 KiB

  prep_w<<<dim3(16), dim3(256), 0, stream>>>(W, Wth, Wtl, DmaxEnc);
  pack_adj<<<dim3(N), dim3(256), 0, stream>>>(adj, packed);
  gemm_fused<<<dim3((M / 64) * H), dim3(256), 0, stream>>>(x, Wth, Wtl, a_src, a_dst,
                                                           Srcv, Epair, DmaxEnc, Ht);
  gat_mfma<<<dim3(B * (N / 32)), dim3(1024), 0, stream>>>((const unsigned char*)packed,
                                                          Srcv, Epair, DmaxEnc, Ht, out);
}